// Round 3
// baseline (9577.296 us; speedup 1.0000x reference)
//
#include <hip/hip_runtime.h>
#include <math.h>

// Shapes (fixed): B=16, Cin=3, C=64, H=W=384, E=768, P=16, G=24, K_sel=64
// Per-batch: conv2 M=147456,N=64,K=576  coarse M=576,N=768,K=16384
//            detail(sel) M=256,N=768,K=4096   merge(all) M=1024,N=768,K=3072

__device__ __forceinline__ float gelu_f(float v){
    return 0.5f*v*(1.0f + erff(v*0.70710678118654752440f));
}

// ---- BN scale/shift precompute: out[0..63]=s1, [64..127]=sh1, [128..191]=s2, [192..255]=sh2
__global__ void bnprep_k(const float* g1,const float* b1,const float* m1,const float* v1,
                         const float* g2,const float* b2,const float* m2,const float* v2,
                         float* outp){
    int t = threadIdx.x;
    if (t < 64){
        float s = g1[t]/sqrtf(v1[t]+1e-5f);
        outp[t] = s; outp[64+t] = b1[t]-m1[t]*s;
        float s2 = g2[t]/sqrtf(v2[t]+1e-5f);
        outp[128+t] = s2; outp[192+t] = b2[t]-m2[t]*s2;
    }
}

// ---- generic 32x32-tiled transpose: in [R][C] -> out [C][R]; R,C multiples of 32
__global__ __launch_bounds__(256) void transpose_k(const float* __restrict__ in,
                                                   float* __restrict__ out, int R, int C){
    __shared__ float t[32][33];
    int tx = threadIdx.x & 31, ty = threadIdx.x >> 5; // 32x8
    int c0 = blockIdx.x*32, r0 = blockIdx.y*32;
    #pragma unroll
    for (int i=0;i<32;i+=8)
        t[ty+i][tx] = in[(r0+ty+i)*C + c0+tx];
    __syncthreads();
    #pragma unroll
    for (int i=0;i<32;i+=8)
        out[(c0+ty+i)*R + r0+tx] = t[tx][ty+i];
}

// ---- conv1 3->64 3x3 SAME + BN + GELU, one thread per pixel, ONE batch image
__global__ __launch_bounds__(256) void conv1_k(const float* __restrict__ x,
                                               const float* __restrict__ w,
                                               const float* __restrict__ bnp,
                                               float* __restrict__ f1b){
    __shared__ float ws[64*27];
    __shared__ float s1[64], sh1[64];
    int tid = threadIdx.x;
    for (int i=tid;i<64*27;i+=256) ws[i] = w[i];
    if (tid < 64){ s1[tid] = bnp[tid]; sh1[tid] = bnp[64+tid]; }
    __syncthreads();
    int p = blockIdx.x*256 + tid;             // pixel over H*W = 147456
    int h = p/384; int wq = p - h*384;
    float xr[27];
    #pragma unroll
    for (int ci=0;ci<3;ci++)
      #pragma unroll
      for (int kh=0;kh<3;kh++)
        #pragma unroll
        for (int kw=0;kw<3;kw++){
            int y = h+kh-1, xx = wq+kw-1;
            float v = 0.f;
            if ((unsigned)y<384u && (unsigned)xx<384u)
                v = x[ci*147456 + y*384 + xx];
            xr[ci*9+kh*3+kw] = v;
        }
    int obase = h*384 + wq;
    for (int co=0;co<64;co++){
        float a = 0.f;
        #pragma unroll
        for (int j=0;j<27;j++) a += xr[j]*ws[co*27+j];
        a = a*s1[co] + sh1[co];
        f1b[obase + co*147456] = gelu_f(a);
    }
}

// ---- templated tiled f32 GEMM, 64x64 tile, BK=16, K-split via blockIdx.z
// MODE 0: conv2 im2col (A=f1b one image), BN+GELU epilogue -> f_b  (no K-split)
// MODE 1: coarse patches (A=f_b) -> partials              (K-split 8)
// MODE 2: detail patches at selected cells (A=f_b, topk) -> partials (K-split 8)
// MODE 3: merge (A=dp, all batches) -> partials           (K-split 4)
template<int MODE>
__global__ __launch_bounds__(256) void gemm_k(const float* __restrict__ A,
                                              const float* __restrict__ Bt,
                                              const int* __restrict__ topk,
                                              float* __restrict__ outp,
                                              const float* __restrict__ bnsc,
                                              const float* __restrict__ bnsh)
{
    constexpr int NTOT = (MODE==0)?64:768;
    constexpr int KLEN = (MODE==0)?576:(MODE==1)?2048:(MODE==2)?512:768;
    constexpr int MTOT = (MODE==1)?576:(MODE==2)?256:1024;   // rows per launch (MODE>=1)
    constexpr int BM=64, BN=64, BK=16, LDA=BM+4;
    __shared__ float As[BK*LDA];
    __shared__ float Bs[BK*BN];
    const int tid = threadIdx.x;
    const int nt = blockIdx.x, mt = blockIdx.y;
    const int tx = tid & 15, ty = tid >> 4;
    const int nb = nt*64;
    const int ks0 = blockIdx.z * KLEN;

    // --- A-load thread mapping precompute ---
    int a_m=0, a_base=0, a_h=0, a_w=0;
    if (MODE==0){
        a_m = tid & 63;
        int gm = mt*64 + a_m;          // pixel within one image
        a_h = gm/384; a_w = gm - a_h*384;
    } else {
        a_m = tid >> 2;
        int r = mt*64 + a_m;           // row within this launch
        if (MODE==1){
            int gy = r/24; int gx = r - gy*24;
            a_base = gy*16*384 + gx*16;
        } else if (MODE==2){
            int ks = r>>2; int dy=(r>>1)&1; int dx=r&1;
            int cell = topk[ks]; int gy = cell/24; int gx = cell - gy*24;
            a_base = (gy*16 + dy*8)*384 + gx*16 + dx*8;
        } else {
            a_base = r*3072;
        }
    }
    const int k0 = (tid&3)*4;

    float acc[4][4];
    #pragma unroll
    for (int i=0;i<4;i++)
        #pragma unroll
        for (int j=0;j<4;j++) acc[i][j]=0.f;

    for (int kb = ks0; kb < ks0 + KLEN; kb += BK){
        // stage A tile (k-major, LDA=68 keeps 16B-aligned rows)
        if (MODE==0){
            #pragma unroll
            for (int i=0;i<4;i++){
                int k = (tid>>6) + 4*i;
                int kk = kb + k;
                int ci = kk/9; int t9 = kk - ci*9; int kh = t9/3; int kw = t9 - kh*3;
                int y = a_h + kh - 1, xx = a_w + kw - 1;
                float v = 0.f;
                if ((unsigned)y<384u && (unsigned)xx<384u)
                    v = A[ci*147456 + y*384 + xx];
                As[k*LDA + a_m] = v;
            }
        } else {
            int kk = kb + k0;
            int src;
            if (MODE==1){ int c = kk>>8; int py=(kk>>4)&15; int px=kk&15;
                          src = a_base + c*147456 + py*384 + px; }
            else if (MODE==2){ int c = kk>>6; int qy=(kk>>3)&7; int qx=kk&7;
                          src = a_base + c*147456 + qy*384 + qx; }
            else { src = a_base + kk; }
            const float4 v = *(const float4*)(A + src);
            As[(k0  )*LDA + a_m] = v.x;
            As[(k0+1)*LDA + a_m] = v.y;
            As[(k0+2)*LDA + a_m] = v.z;
            As[(k0+3)*LDA + a_m] = v.w;
        }
        // stage B tile (already k-major transposed)
        #pragma unroll
        for (int i=0;i<4;i++){
            int e = tid + i*256;
            int k = e>>6, n = e&63;
            Bs[k*BN + n] = Bt[(kb+k)*NTOT + nb + n];
        }
        __syncthreads();
        #pragma unroll
        for (int k=0;k<BK;k++){
            float4 av = *(const float4*)(As + k*LDA + ty*4);
            float4 bv = *(const float4*)(Bs + k*BN + tx*4);
            acc[0][0] += av.x*bv.x; acc[0][1] += av.x*bv.y; acc[0][2] += av.x*bv.z; acc[0][3] += av.x*bv.w;
            acc[1][0] += av.y*bv.x; acc[1][1] += av.y*bv.y; acc[1][2] += av.y*bv.z; acc[1][3] += av.y*bv.w;
            acc[2][0] += av.z*bv.x; acc[2][1] += av.z*bv.y; acc[2][2] += av.z*bv.z; acc[2][3] += av.z*bv.w;
            acc[3][0] += av.w*bv.x; acc[3][1] += av.w*bv.y; acc[3][2] += av.w*bv.z; acc[3][3] += av.w*bv.w;
        }
        __syncthreads();
    }

    // --- epilogue ---
    if (MODE==0){
        int m0 = mt*64;
        int h = m0/384; int w0 = m0 - h*384;
        #pragma unroll
        for (int i=0;i<4;i++){
            int w = w0 + ty*4 + i;
            int base = h*384 + w;
            #pragma unroll
            for (int j=0;j<4;j++){
                int co = tx*4 + j;   // nt==0 for conv2
                float v = acc[i][j]*bnsc[co] + bnsh[co];
                outp[base + co*147456] = gelu_f(v);
            }
        }
    } else {
        float* pout = outp + (size_t)blockIdx.z * MTOT * 768;
        #pragma unroll
        for (int i=0;i<4;i++){
            int gm = mt*64 + ty*4 + i;
            #pragma unroll
            for (int j=0;j<4;j++)
                pout[gm*768 + nb + tx*4 + j] = acc[i][j];
        }
    }
}

// ---- sum K-split partials + bias
__global__ __launch_bounds__(256) void reduce_k(const float* __restrict__ partials,
                                                const float* __restrict__ bias,
                                                float* __restrict__ outp,
                                                int MTOT, int NSPLIT){
    int idx = blockIdx.x*256 + threadIdx.x;   // < MTOT*768
    int col = idx % 768;
    float s = bias[col];
    for (int i=0;i<NSPLIT;i++) s += partials[(size_t)i*MTOT*768 + idx];
    outp[idx] = s;
}

// ---- per-coarse-patch variance score (one batch): block = one (gy,gx)
__global__ __launch_bounds__(256) void var_k(const float* __restrict__ fb,
                                             float* __restrict__ scores){
    __shared__ float buf[4096];     // 16 channels x 256 pixels
    __shared__ float var_s[64];
    int bid = blockIdx.x;           // 0..575
    int gy = bid/24; int gx = bid - gy*24;
    int tid = threadIdx.x;
    int cl = tid>>4, part = tid&15;
    int base = gy*16*384 + gx*16;
    for (int ch=0; ch<64; ch+=16){
        #pragma unroll
        for (int i=0;i<16;i++){
            int e = tid + i*256;
            int c = e>>8; int p = e&255; int py = p>>4; int px = p&15;
            buf[e] = fb[base + (ch+c)*147456 + py*384 + px];
        }
        __syncthreads();
        float s = 0.f;
        #pragma unroll
        for (int j=0;j<16;j++) s += buf[cl*256 + j*16 + part];
        s += __shfl_down(s,8,16); s += __shfl_down(s,4,16);
        s += __shfl_down(s,2,16); s += __shfl_down(s,1,16);
        float mean = __shfl(s,0,16) * (1.f/256.f);
        float q = 0.f;
        #pragma unroll
        for (int j=0;j<16;j++){ float d = buf[cl*256 + j*16 + part] - mean; q += d*d; }
        q += __shfl_down(q,8,16); q += __shfl_down(q,4,16);
        q += __shfl_down(q,2,16); q += __shfl_down(q,1,16);
        if (part==0) var_s[ch+cl] = q*(1.f/256.f);
        __syncthreads();
    }
    if (tid==0){
        float a=0.f;
        for (int c=0;c<64;c++) a += var_s[c];
        scores[bid] = a*(1.f/64.f);
    }
}

// ---- top-64 of 576 (one batch), one wave; jax tie-break (lower idx first)
__global__ void topk_k(const float* __restrict__ scores, int* __restrict__ topk,
                       float* __restrict__ outf){
    int lane = threadIdx.x; // 64
    float v[9];
    #pragma unroll
    for (int j=0;j<9;j++) v[j] = scores[j*64 + lane];
    for (int k=0;k<64;k++){
        float best = -3.0e38f; int bidx = 1<<30;
        #pragma unroll
        for (int j=0;j<9;j++)
            if (v[j] > best){ best = v[j]; bidx = j*64 + lane; }
        #pragma unroll
        for (int off=32; off>0; off>>=1){
            float ov = __shfl_down(best, off);
            int oi   = __shfl_down(bidx, off);
            if (ov > best || (ov == best && oi < bidx)){ best = ov; bidx = oi; }
        }
        bidx = __shfl(bidx, 0);
        if (lane == 0){ topk[k] = bidx; outf[k] = (float)bidx; }
        if ((bidx & 63) == lane) v[bidx>>6] = -3.0e38f;
    }
}

extern "C" void kernel_launch(void* const* d_in, const int* in_sizes, int n_in,
                              void* d_out, int out_size, void* d_ws, size_t ws_size,
                              hipStream_t stream){
    const float* x       = (const float*)d_in[0];
    const float* conv1_w = (const float*)d_in[1];
    const float* bn1_g   = (const float*)d_in[2];
    const float* bn1_b   = (const float*)d_in[3];
    const float* bn1_m   = (const float*)d_in[4];
    const float* bn1_v   = (const float*)d_in[5];
    const float* conv2_w = (const float*)d_in[6];
    const float* bn2_g   = (const float*)d_in[7];
    const float* bn2_b   = (const float*)d_in[8];
    const float* bn2_m   = (const float*)d_in[9];
    const float* bn2_v   = (const float*)d_in[10];
    const float* coarse_w= (const float*)d_in[11];
    const float* coarse_b= (const float*)d_in[12];
    const float* detail_w= (const float*)d_in[13];
    const float* detail_b= (const float*)d_in[14];
    const float* merge_w = (const float*)d_in[15];
    const float* merge_b = (const float*)d_in[16];
    float* out = (float*)d_out;

    // ---- workspace layout (floats); total 43,694,336 floats = 174,777,344 B ----
    float* wsp  = (float*)d_ws;
    float* f1b  = wsp;                    //  9,437,184  (one image, conv1 out)
    float* fb   = f1b + 9437184;          //  9,437,184  (one image, conv2 out)
    float* wt2  = fb  + 9437184;          //     36,864
    float* wtc  = wt2 + 36864;            // 12,582,912
    float* wtd  = wtc + 12582912;         //  3,145,728
    float* wtm  = wtd + 3145728;          //  2,359,296
    float* bnp  = wtm + 2359296;          //        256
    float* scores = bnp + 256;            //      9,216
    int*   topk = (int*)(scores + 9216);  //      1,024
    float* dp   = (float*)(topk + 1024);  //  3,145,728  (all batches, [16*64][3072])
    float* part = dp + 3145728;           //  3,538,944  (K-split partials, max 8*576*768)

    if (ws_size < (size_t)174777344) return;   // diagnostic guard: graceful fail if ws too small

    const int COARSE_OFF = 0;
    const int DETAIL_OFF = 16*576*768;            // 7077888
    const int IDX_OFF    = DETAIL_OFF + 16*64*768;// 7864320

    bnprep_k<<<1,64,0,stream>>>(bn1_g,bn1_b,bn1_m,bn1_v, bn2_g,bn2_b,bn2_m,bn2_v, bnp);
    transpose_k<<<dim3(18,2),256,0,stream>>>(conv2_w, wt2, 64, 576);
    transpose_k<<<dim3(512,24),256,0,stream>>>(coarse_w, wtc, 768, 16384);
    transpose_k<<<dim3(128,24),256,0,stream>>>(detail_w, wtd, 768, 4096);
    transpose_k<<<dim3(96,24),256,0,stream>>>(merge_w,  wtm, 768, 3072);

    for (int b = 0; b < 16; b++){
        conv1_k<<<576,256,0,stream>>>(x + (size_t)b*442368, conv1_w, bnp, f1b);
        gemm_k<0><<<dim3(1,2304),256,0,stream>>>(f1b, wt2, nullptr, fb, bnp+128, bnp+192);
        var_k<<<576,256,0,stream>>>(fb, scores + b*576);
        topk_k<<<1,64,0,stream>>>(scores + b*576, topk + b*64, out + IDX_OFF + b*64);
        // detail at selected cells -> partials -> dp rows [b*256 .. b*256+256)
        gemm_k<2><<<dim3(12,4,8),256,0,stream>>>(fb, wtd, topk + b*64, part, nullptr, nullptr);
        reduce_k<<<768,256,0,stream>>>(part, detail_b, dp + (size_t)b*196608, 256, 8);
        // coarse -> partials -> out rows [b*576 .. b*576+576)
        gemm_k<1><<<dim3(12,9,8),256,0,stream>>>(fb, wtc, nullptr, part, nullptr, nullptr);
        reduce_k<<<1728,256,0,stream>>>(part, coarse_b, out + COARSE_OFF + (size_t)b*442368, 576, 8);
    }

    // merge over all batches: M=1024, K=3072
    gemm_k<3><<<dim3(12,16,4),256,0,stream>>>(dp, wtm, nullptr, part, nullptr, nullptr);
    reduce_k<<<3072,256,0,stream>>>(part, merge_b, out + DETAIL_OFF, 1024, 4);
}

// Round 4
// 6589.362 us; speedup vs baseline: 1.4534x; 1.4534x over previous
//
#include <hip/hip_runtime.h>
#include <math.h>

// Shapes (fixed): B=16, Cin=3, C=64, H=W=384, E=768, P=16, G=24, K_sel=64
// Per-batch: conv2 M=147456,N=64,K=576  coarse(MFMA) M=576,N=768,K=16384
//            detail(sel) M=256,N=768,K=4096   merge(all) M=1024,N=768,K=3072

__device__ __forceinline__ float gelu_f(float v){
    return 0.5f*v*(1.0f + erff(v*0.70710678118654752440f));
}

__device__ __forceinline__ unsigned short f2bf(float v){
    unsigned u = __float_as_uint(v);
    return (unsigned short)((u + 0x7FFFu + ((u>>16)&1u)) >> 16);   // RNE
}

typedef short bf16x8 __attribute__((ext_vector_type(8)));
typedef float f32x4  __attribute__((ext_vector_type(4)));

// ---- BN scale/shift precompute: out[0..63]=s1, [64..127]=sh1, [128..191]=s2, [192..255]=sh2
__global__ void bnprep_k(const float* g1,const float* b1,const float* m1,const float* v1,
                         const float* g2,const float* b2,const float* m2,const float* v2,
                         float* outp){
    int t = threadIdx.x;
    if (t < 64){
        float s = g1[t]/sqrtf(v1[t]+1e-5f);
        outp[t] = s; outp[64+t] = b1[t]-m1[t]*s;
        float s2 = g2[t]/sqrtf(v2[t]+1e-5f);
        outp[128+t] = s2; outp[192+t] = b2[t]-m2[t]*s2;
    }
}

// ---- generic 32x32-tiled transpose: in [R][C] -> out [C][R]; R,C multiples of 32
__global__ __launch_bounds__(256) void transpose_k(const float* __restrict__ in,
                                                   float* __restrict__ out, int R, int C){
    __shared__ float t[32][33];
    int tx = threadIdx.x & 31, ty = threadIdx.x >> 5; // 32x8
    int c0 = blockIdx.x*32, r0 = blockIdx.y*32;
    #pragma unroll
    for (int i=0;i<32;i+=8)
        t[ty+i][tx] = in[(r0+ty+i)*C + c0+tx];
    __syncthreads();
    #pragma unroll
    for (int i=0;i<32;i+=8)
        out[(c0+ty+i)*R + r0+tx] = t[tx][ty+i];
}

// ---- flat f32 -> bf16 convert
__global__ __launch_bounds__(256) void cvtbf16_k(const float* __restrict__ in,
                                                 unsigned short* __restrict__ out, int n){
    int i = blockIdx.x*256 + threadIdx.x;
    if (i < n) out[i] = f2bf(in[i]);
}

// ---- conv1 3->64 3x3 SAME + BN + GELU, one thread per pixel, ONE batch image
__global__ __launch_bounds__(256) void conv1_k(const float* __restrict__ x,
                                               const float* __restrict__ w,
                                               const float* __restrict__ bnp,
                                               float* __restrict__ f1b){
    __shared__ float ws[64*27];
    __shared__ float s1[64], sh1[64];
    int tid = threadIdx.x;
    for (int i=tid;i<64*27;i+=256) ws[i] = w[i];
    if (tid < 64){ s1[tid] = bnp[tid]; sh1[tid] = bnp[64+tid]; }
    __syncthreads();
    int p = blockIdx.x*256 + tid;             // pixel over H*W = 147456
    int h = p/384; int wq = p - h*384;
    float xr[27];
    #pragma unroll
    for (int ci=0;ci<3;ci++)
      #pragma unroll
      for (int kh=0;kh<3;kh++)
        #pragma unroll
        for (int kw=0;kw<3;kw++){
            int y = h+kh-1, xx = wq+kw-1;
            float v = 0.f;
            if ((unsigned)y<384u && (unsigned)xx<384u)
                v = x[ci*147456 + y*384 + xx];
            xr[ci*9+kh*3+kw] = v;
        }
    int obase = h*384 + wq;
    for (int co=0;co<64;co++){
        float a = 0.f;
        #pragma unroll
        for (int j=0;j<27;j++) a += xr[j]*ws[co*27+j];
        a = a*s1[co] + sh1[co];
        f1b[obase + co*147456] = gelu_f(a);
    }
}

// ---- templated tiled f32 GEMM, 64x64 tile, BK=16, K-split via blockIdx.z
// MODE 0: conv2 im2col (A=f1b one image), BN+GELU epilogue -> f_b  (no K-split)
// MODE 2: detail patches at selected cells (A=f_b, topk) -> partials (K-split 8)
// MODE 3: merge (A=dp, all batches) -> partials           (K-split 4)
template<int MODE>
__global__ __launch_bounds__(256) void gemm_k(const float* __restrict__ A,
                                              const float* __restrict__ Bt,
                                              const int* __restrict__ topk,
                                              float* __restrict__ outp,
                                              const float* __restrict__ bnsc,
                                              const float* __restrict__ bnsh)
{
    constexpr int NTOT = (MODE==0)?64:768;
    constexpr int KLEN = (MODE==0)?576:(MODE==2)?512:768;
    constexpr int MTOT = (MODE==2)?256:1024;   // rows per launch (MODE>=2)
    constexpr int BM=64, BN=64, BK=16, LDA=BM+4;
    __shared__ float As[BK*LDA];
    __shared__ float Bs[BK*BN];
    const int tid = threadIdx.x;
    const int nt = blockIdx.x, mt = blockIdx.y;
    const int tx = tid & 15, ty = tid >> 4;
    const int nb = nt*64;
    const int ks0 = blockIdx.z * KLEN;

    int a_m=0, a_base=0, a_h=0, a_w=0;
    if (MODE==0){
        a_m = tid & 63;
        int gm = mt*64 + a_m;          // pixel within one image
        a_h = gm/384; a_w = gm - a_h*384;
    } else {
        a_m = tid >> 2;
        int r = mt*64 + a_m;           // row within this launch
        if (MODE==2){
            int ks = r>>2; int dy=(r>>1)&1; int dx=r&1;
            int cell = topk[ks]; int gy = cell/24; int gx = cell - gy*24;
            a_base = (gy*16 + dy*8)*384 + gx*16 + dx*8;
        } else {
            a_base = r*3072;
        }
    }
    const int k0 = (tid&3)*4;

    float acc[4][4];
    #pragma unroll
    for (int i=0;i<4;i++)
        #pragma unroll
        for (int j=0;j<4;j++) acc[i][j]=0.f;

    for (int kb = ks0; kb < ks0 + KLEN; kb += BK){
        if (MODE==0){
            #pragma unroll
            for (int i=0;i<4;i++){
                int k = (tid>>6) + 4*i;
                int kk = kb + k;
                int ci = kk/9; int t9 = kk - ci*9; int kh = t9/3; int kw = t9 - kh*3;
                int y = a_h + kh - 1, xx = a_w + kw - 1;
                float v = 0.f;
                if ((unsigned)y<384u && (unsigned)xx<384u)
                    v = A[ci*147456 + y*384 + xx];
                As[k*LDA + a_m] = v;
            }
        } else {
            int kk = kb + k0;
            int src;
            if (MODE==2){ int c = kk>>6; int qy=(kk>>3)&7; int qx=kk&7;
                          src = a_base + c*147456 + qy*384 + qx; }
            else { src = a_base + kk; }
            const float4 v = *(const float4*)(A + src);
            As[(k0  )*LDA + a_m] = v.x;
            As[(k0+1)*LDA + a_m] = v.y;
            As[(k0+2)*LDA + a_m] = v.z;
            As[(k0+3)*LDA + a_m] = v.w;
        }
        #pragma unroll
        for (int i=0;i<4;i++){
            int e = tid + i*256;
            int k = e>>6, n = e&63;
            Bs[k*BN + n] = Bt[(kb+k)*NTOT + nb + n];
        }
        __syncthreads();
        #pragma unroll
        for (int k=0;k<BK;k++){
            float4 av = *(const float4*)(As + k*LDA + ty*4);
            float4 bv = *(const float4*)(Bs + k*BN + tx*4);
            acc[0][0] += av.x*bv.x; acc[0][1] += av.x*bv.y; acc[0][2] += av.x*bv.z; acc[0][3] += av.x*bv.w;
            acc[1][0] += av.y*bv.x; acc[1][1] += av.y*bv.y; acc[1][2] += av.y*bv.z; acc[1][3] += av.y*bv.w;
            acc[2][0] += av.z*bv.x; acc[2][1] += av.z*bv.y; acc[2][2] += av.z*bv.z; acc[2][3] += av.z*bv.w;
            acc[3][0] += av.w*bv.x; acc[3][1] += av.w*bv.y; acc[3][2] += av.w*bv.z; acc[3][3] += av.w*bv.w;
        }
        __syncthreads();
    }

    if (MODE==0){
        int m0 = mt*64;
        int h = m0/384; int w0 = m0 - h*384;
        #pragma unroll
        for (int i=0;i<4;i++){
            int w = w0 + ty*4 + i;
            int base = h*384 + w;
            #pragma unroll
            for (int j=0;j<4;j++){
                int co = tx*4 + j;   // nt==0 for conv2
                float v = acc[i][j]*bnsc[co] + bnsh[co];
                outp[base + co*147456] = gelu_f(v);
            }
        }
    } else {
        float* pout = outp + (size_t)blockIdx.z * MTOT * 768;
        #pragma unroll
        for (int i=0;i<4;i++){
            int gm = mt*64 + ty*4 + i;
            #pragma unroll
            for (int j=0;j<4;j++)
                pout[gm*768 + nb + tx*4 + j] = acc[i][j];
        }
    }
}

// ---- patchify: fb (one image f32 [64][384][384]) -> Ac16 [576][16384] bf16
// k-order = c*256 + py*16 + px  (matches coarse_w inner layout)
__global__ __launch_bounds__(256) void patchify_k(const float* __restrict__ fb,
                                                  unsigned short* __restrict__ Ac){
    int r = blockIdx.x;          // cell 0..575
    int gy = r/24, gx = r - gy*24;
    int tid = threadIdx.x;       // 256 = py*16+px
    int py = tid>>4, px = tid&15;
    const float* src = fb + (gy*16+py)*384 + gx*16 + px;
    unsigned short* dst = Ac + (size_t)r*16384 + tid;
    #pragma unroll 4
    for (int c=0;c<64;c++)
        dst[c*256] = f2bf(src[c*147456]);
}

// ---- coarse GEMM via bf16 MFMA: A=Ac16 [576][16384], B=Wc16 [768][16384] (n-major)
// grid (nt=6, mt=9, z=8); block 256 = 4 waves; tile M=64 x N=128; K-split 2048
__global__ __launch_bounds__(256) void coarse_mfma_k(const unsigned short* __restrict__ Ac,
                                                     const unsigned short* __restrict__ Wc,
                                                     float* __restrict__ part){
    __shared__ __align__(16) unsigned short As[64*40];   // rows padded to 40 bf16 (80 B)
    __shared__ __align__(16) unsigned short Bs[128*40];
    const int tid = threadIdx.x;
    const int nt = blockIdx.x, mt = blockIdx.y, z = blockIdx.z;
    const int m0 = mt*64, n0 = nt*128;
    const int wv = tid>>6, lane = tid&63;
    const int lm = lane&15, q = lane>>4;
    const int ar = tid>>2, ak = (tid&3)*8;

    f32x4 acc[4][2];
    #pragma unroll
    for (int i=0;i<4;i++)
        #pragma unroll
        for (int j=0;j<2;j++)
            acc[i][j] = (f32x4){0.f,0.f,0.f,0.f};

    const int kb0 = z*2048;
    for (int kb = kb0; kb < kb0+2048; kb += 32){
        // stage A: 64 rows x 32 k (16B per thread)
        {
            const float4 v = *(const float4*)(Ac + (size_t)(m0+ar)*16384 + kb + ak);
            *(float4*)(&As[ar*40 + ak]) = v;
        }
        // stage B: 128 rows x 32 k
        #pragma unroll
        for (int i=0;i<2;i++){
            const float4 v = *(const float4*)(Wc + (size_t)(n0+ar+i*64)*16384 + kb + ak);
            *(float4*)(&Bs[(ar+i*64)*40 + ak]) = v;
        }
        __syncthreads();
        bf16x8 af[4], bb[2];
        #pragma unroll
        for (int mi=0;mi<4;mi++) af[mi] = *(const bf16x8*)(&As[(mi*16+lm)*40 + q*8]);
        #pragma unroll
        for (int nj=0;nj<2;nj++) bb[nj] = *(const bf16x8*)(&Bs[(wv*32+nj*16+lm)*40 + q*8]);
        #pragma unroll
        for (int mi=0;mi<4;mi++)
            #pragma unroll
            for (int nj=0;nj<2;nj++)
                acc[mi][nj] = __builtin_amdgcn_mfma_f32_16x16x32_bf16(af[mi], bb[nj], acc[mi][nj], 0,0,0);
        __syncthreads();
    }

    float* pz = part + (size_t)z*576*768;
    #pragma unroll
    for (int mi=0;mi<4;mi++)
        #pragma unroll
        for (int nj=0;nj<2;nj++)
            #pragma unroll
            for (int r=0;r<4;r++){
                int m = m0 + mi*16 + q*4 + r;
                int n = n0 + wv*32 + nj*16 + lm;
                pz[m*768 + n] = acc[mi][nj][r];
            }
}

// ---- sum K-split partials + bias
__global__ __launch_bounds__(256) void reduce_k(const float* __restrict__ partials,
                                                const float* __restrict__ bias,
                                                float* __restrict__ outp,
                                                int MTOT, int NSPLIT){
    int idx = blockIdx.x*256 + threadIdx.x;   // < MTOT*768
    int col = idx % 768;
    float s = bias[col];
    for (int i=0;i<NSPLIT;i++) s += partials[(size_t)i*MTOT*768 + idx];
    outp[idx] = s;
}

// ---- per-coarse-patch variance score (one batch): block = one (gy,gx)
__global__ __launch_bounds__(256) void var_k(const float* __restrict__ fb,
                                             float* __restrict__ scores){
    __shared__ float buf[4096];     // 16 channels x 256 pixels
    __shared__ float var_s[64];
    int bid = blockIdx.x;           // 0..575
    int gy = bid/24; int gx = bid - gy*24;
    int tid = threadIdx.x;
    int cl = tid>>4, part = tid&15;
    int base = gy*16*384 + gx*16;
    for (int ch=0; ch<64; ch+=16){
        #pragma unroll
        for (int i=0;i<16;i++){
            int e = tid + i*256;
            int c = e>>8; int p = e&255; int py = p>>4; int px = p&15;
            buf[e] = fb[base + (ch+c)*147456 + py*384 + px];
        }
        __syncthreads();
        float s = 0.f;
        #pragma unroll
        for (int j=0;j<16;j++) s += buf[cl*256 + j*16 + part];
        s += __shfl_down(s,8,16); s += __shfl_down(s,4,16);
        s += __shfl_down(s,2,16); s += __shfl_down(s,1,16);
        float mean = __shfl(s,0,16) * (1.f/256.f);
        float q = 0.f;
        #pragma unroll
        for (int j=0;j<16;j++){ float d = buf[cl*256 + j*16 + part] - mean; q += d*d; }
        q += __shfl_down(q,8,16); q += __shfl_down(q,4,16);
        q += __shfl_down(q,2,16); q += __shfl_down(q,1,16);
        if (part==0) var_s[ch+cl] = q*(1.f/256.f);
        __syncthreads();
    }
    if (tid==0){
        float a=0.f;
        for (int c=0;c<64;c++) a += var_s[c];
        scores[bid] = a*(1.f/64.f);
    }
}

// ---- top-64 of 576 (one batch), one wave; jax tie-break (lower idx first)
__global__ void topk_k(const float* __restrict__ scores, int* __restrict__ topk,
                       float* __restrict__ outf){
    int lane = threadIdx.x; // 64
    float v[9];
    #pragma unroll
    for (int j=0;j<9;j++) v[j] = scores[j*64 + lane];
    for (int k=0;k<64;k++){
        float best = -3.0e38f; int bidx = 1<<30;
        #pragma unroll
        for (int j=0;j<9;j++)
            if (v[j] > best){ best = v[j]; bidx = j*64 + lane; }
        #pragma unroll
        for (int off=32; off>0; off>>=1){
            float ov = __shfl_down(best, off);
            int oi   = __shfl_down(bidx, off);
            if (ov > best || (ov == best && oi < bidx)){ best = ov; bidx = oi; }
        }
        bidx = __shfl(bidx, 0);
        if (lane == 0){ topk[k] = bidx; outf[k] = (float)bidx; }
        if ((bidx & 63) == lane) v[bidx>>6] = -3.0e38f;
    }
}

extern "C" void kernel_launch(void* const* d_in, const int* in_sizes, int n_in,
                              void* d_out, int out_size, void* d_ws, size_t ws_size,
                              hipStream_t stream){
    const float* x       = (const float*)d_in[0];
    const float* conv1_w = (const float*)d_in[1];
    const float* bn1_g   = (const float*)d_in[2];
    const float* bn1_b   = (const float*)d_in[3];
    const float* bn1_m   = (const float*)d_in[4];
    const float* bn1_v   = (const float*)d_in[5];
    const float* conv2_w = (const float*)d_in[6];
    const float* bn2_g   = (const float*)d_in[7];
    const float* bn2_b   = (const float*)d_in[8];
    const float* bn2_m   = (const float*)d_in[9];
    const float* bn2_v   = (const float*)d_in[10];
    const float* coarse_w= (const float*)d_in[11];
    const float* coarse_b= (const float*)d_in[12];
    const float* detail_w= (const float*)d_in[13];
    const float* detail_b= (const float*)d_in[14];
    const float* merge_w = (const float*)d_in[15];
    const float* merge_b = (const float*)d_in[16];
    float* out = (float*)d_out;

    // ---- workspace layout (float units); total 42,121,472 floats = 168,485,888 B ----
    float* wsp  = (float*)d_ws;
    float* f1b  = wsp;                    //  9,437,184
    float* fb   = f1b + 9437184;          //  9,437,184
    float* wt2  = fb  + 9437184;          //     36,864
    float* wtd  = wt2 + 36864;            //  3,145,728
    float* wtm  = wtd + 3145728;          //  2,359,296
    float* bnp  = wtm + 2359296;          //        256
    float* scores = bnp + 256;            //      9,216
    int*   topk = (int*)(scores + 9216);  //      1,024
    float* dp   = (float*)(topk + 1024);  //  3,145,728
    float* part = dp + 3145728;           //  3,538,944 (max 8*576*768)
    unsigned short* Wc16 = (unsigned short*)(part + 3538944); // 12,582,912 bf16
    unsigned short* Ac16 = Wc16 + 12582912;                   //  9,437,184 bf16

    if (ws_size < (size_t)168485888) return;   // graceful fail if ws too small

    const int COARSE_OFF = 0;
    const int DETAIL_OFF = 16*576*768;            // 7077888
    const int IDX_OFF    = DETAIL_OFF + 16*64*768;// 7864320

    bnprep_k<<<1,64,0,stream>>>(bn1_g,bn1_b,bn1_m,bn1_v, bn2_g,bn2_b,bn2_m,bn2_v, bnp);
    transpose_k<<<dim3(18,2),256,0,stream>>>(conv2_w, wt2, 64, 576);
    transpose_k<<<dim3(128,24),256,0,stream>>>(detail_w, wtd, 768, 4096);
    transpose_k<<<dim3(96,24),256,0,stream>>>(merge_w,  wtm, 768, 3072);
    cvtbf16_k<<<49152,256,0,stream>>>(coarse_w, Wc16, 12582912);

    for (int b = 0; b < 16; b++){
        conv1_k<<<576,256,0,stream>>>(x + (size_t)b*442368, conv1_w, bnp, f1b);
        gemm_k<0><<<dim3(1,2304),256,0,stream>>>(f1b, wt2, nullptr, fb, bnp+128, bnp+192);
        var_k<<<576,256,0,stream>>>(fb, scores + b*576);
        topk_k<<<1,64,0,stream>>>(scores + b*576, topk + b*64, out + IDX_OFF + b*64);
        // detail at selected cells -> partials -> dp rows [b*256 ..)
        gemm_k<2><<<dim3(12,4,8),256,0,stream>>>(fb, wtd, topk + b*64, part, nullptr, nullptr);
        reduce_k<<<768,256,0,stream>>>(part, detail_b, dp + (size_t)b*196608, 256, 8);
        // coarse via bf16 MFMA
        patchify_k<<<576,256,0,stream>>>(fb, Ac16);
        coarse_mfma_k<<<dim3(6,9,8),256,0,stream>>>(Ac16, Wc16, part);
        reduce_k<<<1728,256,0,stream>>>(part, coarse_b, out + COARSE_OFF + (size_t)b*442368, 576, 8);
    }

    // merge over all batches: M=1024, K=3072
    gemm_k<3><<<dim3(12,16,4),256,0,stream>>>(dp, wtm, nullptr, part, nullptr, nullptr);
    reduce_k<<<3072,256,0,stream>>>(part, merge_b, out + DETAIL_OFF, 1024, 4);
}

// Round 5
// 5942.475 us; speedup vs baseline: 1.6117x; 1.1089x over previous
//
#include <hip/hip_runtime.h>
#include <math.h>

// Shapes (fixed): B=16, Cin=3, C=64, H=W=384, E=768, P=16, G=24, K_sel=64
// conv2 (per-b, MFMA split-2 bf16): M=147456, N=64, K=576
// coarse: M=576,N=768,K=16384  detail(sel): M=256,N=768,K=4096  merge: M=1024,N=768,K=3072

__device__ __forceinline__ float gelu_f(float v){
    return 0.5f*v*(1.0f + erff(v*0.70710678118654752440f));
}
__device__ __forceinline__ unsigned short f2bf(float v){
    unsigned u = __float_as_uint(v);
    return (unsigned short)((u + 0x7FFFu + ((u>>16)&1u)) >> 16);   // RNE
}
__device__ __forceinline__ float bf2f(unsigned short h){
    return __uint_as_float(((unsigned)h)<<16);
}
__device__ __forceinline__ void split2(float v, unsigned short& hi, unsigned short& lo){
    hi = f2bf(v);
    lo = f2bf(v - bf2f(hi));
}

typedef short bf16x8 __attribute__((ext_vector_type(8)));
typedef float f32x4  __attribute__((ext_vector_type(4)));

// ---- BN scale/shift: out[0..63]=s1, [64..127]=sh1, [128..191]=s2, [192..255]=sh2
__global__ void bnprep_k(const float* g1,const float* b1,const float* m1,const float* v1,
                         const float* g2,const float* b2,const float* m2,const float* v2,
                         float* outp){
    int t = threadIdx.x;
    if (t < 64){
        float s = g1[t]/sqrtf(v1[t]+1e-5f);
        outp[t] = s; outp[64+t] = b1[t]-m1[t]*s;
        float s2 = g2[t]/sqrtf(v2[t]+1e-5f);
        outp[128+t] = s2; outp[192+t] = b2[t]-m2[t]*s2;
    }
}

// ---- conv2 weights -> split-2 bf16, n-major [64][576], k' = (kh*3+kw)*64 + ci
__global__ void w2prep_k(const float* __restrict__ w,
                         unsigned short* __restrict__ bhi, unsigned short* __restrict__ blo){
    int idx = blockIdx.x*256 + threadIdx.x;
    if (idx >= 36864) return;
    int n = idx/576, kp = idx - n*576;
    int t = kp>>6, ci = kp&63; int kh = t/3, kw = t - kh*3;
    float v = w[((n*64+ci)*3+kh)*3+kw];
    unsigned short hi,lo; split2(v,hi,lo);
    bhi[n*576+kp]=hi; blo[n*576+kp]=lo;
}

// ---- flat f32 -> bf16 convert
__global__ __launch_bounds__(256) void cvtbf16_k(const float* __restrict__ in,
                                                 unsigned short* __restrict__ out, int n){
    int i = blockIdx.x*256 + threadIdx.x;
    if (i < n) out[i] = f2bf(in[i]);
}

// ---- conv1 3->64 3x3 SAME + BN + GELU; writes NHWC split-2 bf16 planes (one image)
__global__ __launch_bounds__(256) void conv1_k(const float* __restrict__ x,
                                               const float* __restrict__ w,
                                               const float* __restrict__ bnp,
                                               unsigned short* __restrict__ f1hi,
                                               unsigned short* __restrict__ f1lo){
    __shared__ float ws[64*27];
    __shared__ float s1[64], sh1[64];
    int tid = threadIdx.x;
    for (int i=tid;i<64*27;i+=256) ws[i] = w[i];
    if (tid < 64){ s1[tid] = bnp[tid]; sh1[tid] = bnp[64+tid]; }
    __syncthreads();
    int p = blockIdx.x*256 + tid;             // pixel over H*W = 147456
    int h = p/384; int wq = p - h*384;
    float xr[27];
    #pragma unroll
    for (int ci=0;ci<3;ci++)
      #pragma unroll
      for (int kh=0;kh<3;kh++)
        #pragma unroll
        for (int kw=0;kw<3;kw++){
            int y = h+kh-1, xx = wq+kw-1;
            float v = 0.f;
            if ((unsigned)y<384u && (unsigned)xx<384u)
                v = x[ci*147456 + y*384 + xx];
            xr[ci*9+kh*3+kw] = v;
        }
    size_t base = (size_t)p*64;
    for (int g=0; g<8; g++){
        unsigned short hs[8], ls[8];
        #pragma unroll
        for (int j=0;j<8;j++){
            int co = g*8+j;
            float a = 0.f;
            #pragma unroll
            for (int k=0;k<27;k++) a += xr[k]*ws[co*27+k];
            a = gelu_f(a*s1[co] + sh1[co]);
            split2(a, hs[j], ls[j]);
        }
        *(float4*)(f1hi + base + g*8) = *(float4*)hs;
        *(float4*)(f1lo + base + g*8) = *(float4*)ls;
    }
}

// ---- conv2 via split-2 bf16 MFMA (3 passes). One image.
// M-tile 192 (one row y, x0=0 or 192), N=64, K = 9 taps x 64 ci.
// Block 192 thr = 3 waves, wave tile 64m x 64n.
__global__ __launch_bounds__(192) void conv2_mfma_k(
        const unsigned short* __restrict__ f1hi, const unsigned short* __restrict__ f1lo,
        const unsigned short* __restrict__ bhi,  const unsigned short* __restrict__ blo,
        const float* __restrict__ bnsc, const float* __restrict__ bnsh,
        float* __restrict__ fb){
    __shared__ __align__(16) unsigned short Ah[192*68], Al[192*68];
    __shared__ __align__(16) unsigned short Bh[64*68],  Bl[64*68];
    const int tid = threadIdx.x;
    const int bm = blockIdx.x*192;
    const int y = bm/384, x0 = bm - y*384;     // x0 in {0,192}
    const int wv = tid>>6, lane = tid&63, lm = lane&15, q = lane>>4;

    f32x4 acc[4][4];
    #pragma unroll
    for (int i=0;i<4;i++)
        #pragma unroll
        for (int j=0;j<4;j++) acc[i][j] = (f32x4){0.f,0.f,0.f,0.f};

    for (int t9=0; t9<9; t9++){
        int kh = t9/3, kw = t9 - kh*3;
        int ys = y + kh - 1;
        bool yok = ((unsigned)ys < 384u);
        // stage A: 192 px x 64 c, hi+lo (16B chunks)
        #pragma unroll
        for (int i=0;i<8;i++){
            int ch = tid + i*192;
            int pr = ch>>3, c8 = (ch&7)*8;
            int xs = x0 + pr + kw - 1;
            float4 vh = {0.f,0.f,0.f,0.f}, vl = {0.f,0.f,0.f,0.f};
            if (yok && (unsigned)xs < 384u){
                size_t off = ((size_t)(ys*384 + xs))*64 + c8;
                vh = *(const float4*)(f1hi + off);
                vl = *(const float4*)(f1lo + off);
            }
            *(float4*)(Ah + pr*68 + c8) = vh;
            *(float4*)(Al + pr*68 + c8) = vl;
        }
        // stage B: 64 n x 64 c, hi+lo
        #pragma unroll
        for (int i=0;i<3;i++){
            int ch = tid + i*192;
            if (ch < 512){
                int n = ch>>3, c8 = (ch&7)*8;
                size_t off = (size_t)n*576 + t9*64 + c8;
                *(float4*)(Bh + n*68 + c8) = *(const float4*)(bhi + off);
                *(float4*)(Bl + n*68 + c8) = *(const float4*)(blo + off);
            }
        }
        __syncthreads();
        #pragma unroll
        for (int h=0; h<2; h++){
            bf16x8 ah[4], al[4], bh8[4], bl8[4];
            #pragma unroll
            for (int mi=0;mi<4;mi++){
                int row = wv*64 + mi*16 + lm;
                ah[mi] = *(const bf16x8*)(Ah + row*68 + h*32 + q*8);
                al[mi] = *(const bf16x8*)(Al + row*68 + h*32 + q*8);
            }
            #pragma unroll
            for (int nj=0;nj<4;nj++){
                int row = nj*16 + lm;
                bh8[nj] = *(const bf16x8*)(Bh + row*68 + h*32 + q*8);
                bl8[nj] = *(const bf16x8*)(Bl + row*68 + h*32 + q*8);
            }
            #pragma unroll
            for (int mi=0;mi<4;mi++)
                #pragma unroll
                for (int nj=0;nj<4;nj++){
                    acc[mi][nj] = __builtin_amdgcn_mfma_f32_16x16x32_bf16(ah[mi], bh8[nj], acc[mi][nj], 0,0,0);
                    acc[mi][nj] = __builtin_amdgcn_mfma_f32_16x16x32_bf16(al[mi], bh8[nj], acc[mi][nj], 0,0,0);
                    acc[mi][nj] = __builtin_amdgcn_mfma_f32_16x16x32_bf16(ah[mi], bl8[nj], acc[mi][nj], 0,0,0);
                }
        }
        __syncthreads();
    }
    // epilogue: BN + GELU -> fb NCHW f32
    #pragma unroll
    for (int nj=0;nj<4;nj++){
        int n = nj*16 + lm;
        float sc = bnsc[n], sh = bnsh[n];
        #pragma unroll
        for (int mi=0;mi<4;mi++){
            int m0 = bm + wv*64 + mi*16 + q*4;
            float4 o;
            o.x = gelu_f(acc[mi][nj][0]*sc + sh);
            o.y = gelu_f(acc[mi][nj][1]*sc + sh);
            o.z = gelu_f(acc[mi][nj][2]*sc + sh);
            o.w = gelu_f(acc[mi][nj][3]*sc + sh);
            *(float4*)(fb + (size_t)n*147456 + m0) = o;
        }
    }
}

// ---- patchify coarse: fb f32 -> Ac16 [576][16384] bf16, k = c*256+py*16+px
__global__ __launch_bounds__(256) void patchify_k(const float* __restrict__ fb,
                                                  unsigned short* __restrict__ Ac){
    int r = blockIdx.x;          // cell 0..575
    int gy = r/24, gx = r - gy*24;
    int tid = threadIdx.x;       // 256 = py*16+px
    int py = tid>>4, px = tid&15;
    const float* src = fb + (gy*16+py)*384 + gx*16 + px;
    unsigned short* dst = Ac + (size_t)r*16384 + tid;
    #pragma unroll 4
    for (int c=0;c<64;c++)
        dst[c*256] = f2bf(src[c*147456]);
}

// ---- patchify detail: fb f32 -> Ad16 [2304][4096] bf16; row = cell*4+dy*2+dx, k = c*64+qy*8+qx
__global__ __launch_bounds__(256) void patchify_d_k(const float* __restrict__ fb,
                                                    unsigned short* __restrict__ Ad){
    int r = blockIdx.x;          // 0..2303
    int cell = r>>2; int gy = cell/24, gx = cell - gy*24;
    int dy = (r>>1)&1, dx = r&1;
    int base = (gy*16+dy*8)*384 + gx*16 + dx*8;
    int tid = threadIdx.x;
    #pragma unroll
    for (int i=0;i<16;i++){
        int k = tid + i*256;
        int c = k>>6, qy = (k>>3)&7, qx = k&7;
        Ad[(size_t)r*4096 + k] = f2bf(fb[c*147456 + base + qy*384 + qx]);
    }
}

// ---- generic bf16 MFMA GEMM: tile M=64 x N=128, block 256 thr (4 waves), K-split z
// A row-major [rows][KT] bf16; W n-major [768][KT] bf16 -> partials [z][MT][768] f32
// MODE 0: coarse (row = m0+ar); MODE 1: detail (row = topk[(m0+ar)>>2]*4 + ((m0+ar)&3)); MODE 2: merge
template<int MODE, int KT, int KL, int MT>
__global__ __launch_bounds__(256) void gemm16_k(const unsigned short* __restrict__ A,
                                                const unsigned short* __restrict__ W,
                                                const int* __restrict__ topk,
                                                float* __restrict__ part){
    __shared__ __align__(16) unsigned short As[64*40];
    __shared__ __align__(16) unsigned short Bs[128*40];
    const int tid = threadIdx.x;
    const int nt = blockIdx.x, mt = blockIdx.y, z = blockIdx.z;
    const int m0 = mt*64, n0 = nt*128;
    const int wv = tid>>6, lane = tid&63;
    const int lm = lane&15, q = lane>>4;
    const int ar = tid>>2, ak = (tid&3)*8;

    int arow = m0 + ar;
    if (MODE==1) arow = topk[(m0+ar)>>2]*4 + ((m0+ar)&3);

    f32x4 acc[4][2];
    #pragma unroll
    for (int i=0;i<4;i++)
        #pragma unroll
        for (int j=0;j<2;j++)
            acc[i][j] = (f32x4){0.f,0.f,0.f,0.f};

    const int kb0 = z*KL;
    for (int kb = kb0; kb < kb0+KL; kb += 32){
        {
            const float4 v = *(const float4*)(A + (size_t)arow*KT + kb + ak);
            *(float4*)(&As[ar*40 + ak]) = v;
        }
        #pragma unroll
        for (int i=0;i<2;i++){
            const float4 v = *(const float4*)(W + (size_t)(n0+ar+i*64)*KT + kb + ak);
            *(float4*)(&Bs[(ar+i*64)*40 + ak]) = v;
        }
        __syncthreads();
        bf16x8 af[4], bb[2];
        #pragma unroll
        for (int mi=0;mi<4;mi++) af[mi] = *(const bf16x8*)(&As[(mi*16+lm)*40 + q*8]);
        #pragma unroll
        for (int nj=0;nj<2;nj++) bb[nj] = *(const bf16x8*)(&Bs[(wv*32+nj*16+lm)*40 + q*8]);
        #pragma unroll
        for (int mi=0;mi<4;mi++)
            #pragma unroll
            for (int nj=0;nj<2;nj++)
                acc[mi][nj] = __builtin_amdgcn_mfma_f32_16x16x32_bf16(af[mi], bb[nj], acc[mi][nj], 0,0,0);
        __syncthreads();
    }

    float* pz = part + (size_t)z*MT*768;
    #pragma unroll
    for (int mi=0;mi<4;mi++)
        #pragma unroll
        for (int nj=0;nj<2;nj++)
            #pragma unroll
            for (int r=0;r<4;r++){
                int m = m0 + mi*16 + q*4 + r;
                int n = n0 + wv*32 + nj*16 + lm;
                pz[m*768 + n] = acc[mi][nj][r];
            }
}

// ---- sum K-split partials + bias -> f32
__global__ __launch_bounds__(256) void reduce_k(const float* __restrict__ partials,
                                                const float* __restrict__ bias,
                                                float* __restrict__ outp,
                                                int MTOT, int NSPLIT){
    int idx = blockIdx.x*256 + threadIdx.x;
    int col = idx % 768;
    float s = bias[col];
    for (int i=0;i<NSPLIT;i++) s += partials[(size_t)i*MTOT*768 + idx];
    outp[idx] = s;
}

// ---- sum K-split partials + bias -> bf16
__global__ __launch_bounds__(256) void reduce16_k(const float* __restrict__ partials,
                                                  const float* __restrict__ bias,
                                                  unsigned short* __restrict__ outp,
                                                  int MTOT, int NSPLIT){
    int idx = blockIdx.x*256 + threadIdx.x;
    int col = idx % 768;
    float s = bias[col];
    for (int i=0;i<NSPLIT;i++) s += partials[(size_t)i*MTOT*768 + idx];
    outp[idx] = f2bf(s);
}

// ---- per-coarse-patch variance score (one batch)
__global__ __launch_bounds__(256) void var_k(const float* __restrict__ fb,
                                             float* __restrict__ scores){
    __shared__ float buf[4096];
    __shared__ float var_s[64];
    int bid = blockIdx.x;           // 0..575
    int gy = bid/24; int gx = bid - gy*24;
    int tid = threadIdx.x;
    int cl = tid>>4, part = tid&15;
    int base = gy*16*384 + gx*16;
    for (int ch=0; ch<64; ch+=16){
        #pragma unroll
        for (int i=0;i<16;i++){
            int e = tid + i*256;
            int c = e>>8; int p = e&255; int py = p>>4; int px = p&15;
            buf[e] = fb[base + (ch+c)*147456 + py*384 + px];
        }
        __syncthreads();
        float s = 0.f;
        #pragma unroll
        for (int j=0;j<16;j++) s += buf[cl*256 + j*16 + part];
        s += __shfl_down(s,8,16); s += __shfl_down(s,4,16);
        s += __shfl_down(s,2,16); s += __shfl_down(s,1,16);
        float mean = __shfl(s,0,16) * (1.f/256.f);
        float q = 0.f;
        #pragma unroll
        for (int j=0;j<16;j++){ float d = buf[cl*256 + j*16 + part] - mean; q += d*d; }
        q += __shfl_down(q,8,16); q += __shfl_down(q,4,16);
        q += __shfl_down(q,2,16); q += __shfl_down(q,1,16);
        if (part==0) var_s[ch+cl] = q*(1.f/256.f);
        __syncthreads();
    }
    if (tid==0){
        float a=0.f;
        for (int c=0;c<64;c++) a += var_s[c];
        scores[bid] = a*(1.f/64.f);
    }
}

// ---- top-64 of 576 (one batch), one wave; jax tie-break (lower idx first)
__global__ void topk_k(const float* __restrict__ scores, int* __restrict__ topk,
                       float* __restrict__ outf){
    int lane = threadIdx.x; // 64
    float v[9];
    #pragma unroll
    for (int j=0;j<9;j++) v[j] = scores[j*64 + lane];
    for (int k=0;k<64;k++){
        float best = -3.0e38f; int bidx = 1<<30;
        #pragma unroll
        for (int j=0;j<9;j++)
            if (v[j] > best){ best = v[j]; bidx = j*64 + lane; }
        #pragma unroll
        for (int off=32; off>0; off>>=1){
            float ov = __shfl_down(best, off);
            int oi   = __shfl_down(bidx, off);
            if (ov > best || (ov == best && oi < bidx)){ best = ov; bidx = oi; }
        }
        bidx = __shfl(bidx, 0);
        if (lane == 0){ topk[k] = bidx; outf[k] = (float)bidx; }
        if ((bidx & 63) == lane) v[bidx>>6] = -3.0e38f;
    }
}

extern "C" void kernel_launch(void* const* d_in, const int* in_sizes, int n_in,
                              void* d_out, int out_size, void* d_ws, size_t ws_size,
                              hipStream_t stream){
    const float* x       = (const float*)d_in[0];
    const float* conv1_w = (const float*)d_in[1];
    const float* bn1_g   = (const float*)d_in[2];
    const float* bn1_b   = (const float*)d_in[3];
    const float* bn1_m   = (const float*)d_in[4];
    const float* bn1_v   = (const float*)d_in[5];
    const float* conv2_w = (const float*)d_in[6];
    const float* bn2_g   = (const float*)d_in[7];
    const float* bn2_b   = (const float*)d_in[8];
    const float* bn2_m   = (const float*)d_in[9];
    const float* bn2_v   = (const float*)d_in[10];
    const float* coarse_w= (const float*)d_in[11];
    const float* coarse_b= (const float*)d_in[12];
    const float* detail_w= (const float*)d_in[13];
    const float* detail_b= (const float*)d_in[14];
    const float* merge_w = (const float*)d_in[15];
    const float* merge_b = (const float*)d_in[16];
    float* out = (float*)d_out;

    // ---- workspace layout (float units); total 42,514,688 fl = 170,058,752 B (ws >= 174,777,344 known) ----
    float* wsp  = (float*)d_ws;
    unsigned short* f1hi = (unsigned short*)wsp;         // 9,437,184 bf16
    unsigned short* f1lo = f1hi + 9437184;               // 9,437,184 bf16
    float* fb   = wsp + 9437184;                         // 9,437,184 f32
    float* bnp  = fb + 9437184;                          // 256
    float* scores = bnp + 256;                           // 9,216
    int*   topk = (int*)(scores + 9216);                 // 1,024
    unsigned short* B2hi = (unsigned short*)(topk + 1024);   // 36,864 bf16
    unsigned short* B2lo = B2hi + 36864;                     // 36,864 bf16
    unsigned short* Wc16 = B2lo + 36864;                     // 12,582,912 bf16
    unsigned short* Wd16 = Wc16 + 12582912;                  // 3,145,728 bf16
    unsigned short* Wm16 = Wd16 + 3145728;                   // 2,359,296 bf16
    unsigned short* Ac16 = Wm16 + 2359296;                   // 9,437,184 bf16
    unsigned short* Ad16 = Ac16 + 9437184;                   // 9,437,184 bf16
    unsigned short* dp16 = Ad16 + 9437184;                   // 3,145,728 bf16
    float* part = (float*)(dp16 + 3145728);                  // 3,538,944 f32

    if (ws_size < (size_t)171000000) return;   // graceful fail if ws too small

    const int DETAIL_OFF = 16*576*768;            // 7077888
    const int IDX_OFF    = DETAIL_OFF + 16*64*768;// 7864320

    bnprep_k<<<1,64,0,stream>>>(bn1_g,bn1_b,bn1_m,bn1_v, bn2_g,bn2_b,bn2_m,bn2_v, bnp);
    w2prep_k<<<144,256,0,stream>>>(conv2_w, B2hi, B2lo);
    cvtbf16_k<<<49152,256,0,stream>>>(coarse_w, Wc16, 12582912);
    cvtbf16_k<<<12288,256,0,stream>>>(detail_w, Wd16, 3145728);
    cvtbf16_k<<<9216,256,0,stream>>>(merge_w,  Wm16, 2359296);

    for (int b = 0; b < 16; b++){
        conv1_k<<<576,256,0,stream>>>(x + (size_t)b*442368, conv1_w, bnp, f1hi, f1lo);
        conv2_mfma_k<<<768,192,0,stream>>>(f1hi, f1lo, B2hi, B2lo, bnp+128, bnp+192, fb);
        var_k<<<576,256,0,stream>>>(fb, scores + b*576);
        topk_k<<<1,64,0,stream>>>(scores + b*576, topk + b*64, out + IDX_OFF + b*64);
        // coarse tokens
        patchify_k<<<576,256,0,stream>>>(fb, Ac16);
        gemm16_k<0,16384,2048,576><<<dim3(6,9,8),256,0,stream>>>(Ac16, Wc16, nullptr, part);
        reduce_k<<<1728,256,0,stream>>>(part, coarse_b, out + (size_t)b*442368, 576, 8);
        // detail tokens (selected)
        patchify_d_k<<<2304,256,0,stream>>>(fb, Ad16);
        gemm16_k<1,4096,1024,256><<<dim3(6,4,4),256,0,stream>>>(Ad16, Wd16, topk + b*64, part);
        reduce16_k<<<768,256,0,stream>>>(part, detail_b, dp16 + (size_t)b*196608, 256, 4);
    }

    // merge over all batches: M=1024, K=3072
    gemm16_k<2,3072,768,1024><<<dim3(6,16,4),256,0,stream>>>(dp16, Wm16, nullptr, part);
    reduce_k<<<3072,256,0,stream>>>(part, merge_b, out + DETAIL_OFF, 1024, 4);
}

// Round 6
// 4704.250 us; speedup vs baseline: 2.0359x; 1.2632x over previous
//
#include <hip/hip_runtime.h>
#include <math.h>

// Shapes (fixed): B=16, Cin=3, C=64, H=W=384, E=768, P=16, G=24, K_sel=64
// conv2 (per-b, MFMA split-2 bf16): M=147456, N=64, K=576
// coarse: M=576,N=768,K=16384  detail(sel): M=256,N=768,K=4096  merge: M=1024,N=768,K=3072

__device__ __forceinline__ float gelu_f(float v){
    return 0.5f*v*(1.0f + erff(v*0.70710678118654752440f));
}
__device__ __forceinline__ unsigned short f2bf(float v){
    unsigned u = __float_as_uint(v);
    return (unsigned short)((u + 0x7FFFu + ((u>>16)&1u)) >> 16);   // RNE
}
__device__ __forceinline__ float bf2f(unsigned short h){
    return __uint_as_float(((unsigned)h)<<16);
}
__device__ __forceinline__ void split2(float v, unsigned short& hi, unsigned short& lo){
    hi = f2bf(v);
    lo = f2bf(v - bf2f(hi));
}

typedef short bf16x8 __attribute__((ext_vector_type(8)));
typedef float f32x4  __attribute__((ext_vector_type(4)));

// ---- BN scale/shift: out[0..63]=s1, [64..127]=sh1, [128..191]=s2, [192..255]=sh2
__global__ void bnprep_k(const float* g1,const float* b1,const float* m1,const float* v1,
                         const float* g2,const float* b2,const float* m2,const float* v2,
                         float* outp){
    int t = threadIdx.x;
    if (t < 64){
        float s = g1[t]/sqrtf(v1[t]+1e-5f);
        outp[t] = s; outp[64+t] = b1[t]-m1[t]*s;
        float s2 = g2[t]/sqrtf(v2[t]+1e-5f);
        outp[128+t] = s2; outp[192+t] = b2[t]-m2[t]*s2;
    }
}

// ---- conv2 weights -> split-2 bf16, n-major [64][576], k' = (kh*3+kw)*64 + ci
__global__ void w2prep_k(const float* __restrict__ w,
                         unsigned short* __restrict__ bhi, unsigned short* __restrict__ blo){
    int idx = blockIdx.x*256 + threadIdx.x;
    if (idx >= 36864) return;
    int n = idx/576, kp = idx - n*576;
    int t = kp>>6, ci = kp&63; int kh = t/3, kw = t - kh*3;
    float v = w[((n*64+ci)*3+kh)*3+kw];
    unsigned short hi,lo; split2(v,hi,lo);
    bhi[n*576+kp]=hi; blo[n*576+kp]=lo;
}

// ---- flat f32 -> bf16 convert
__global__ __launch_bounds__(256) void cvtbf16_k(const float* __restrict__ in,
                                                 unsigned short* __restrict__ out, int n){
    int i = blockIdx.x*256 + threadIdx.x;
    if (i < n) out[i] = f2bf(in[i]);
}

// ---- conv1 3->64 3x3 SAME + BN + GELU; NHWC split-2 bf16 (one image)
// block = 32 pixels x 8 channel-groups -> stores are lane-contiguous (coalesced)
__global__ __launch_bounds__(256) void conv1_k(const float* __restrict__ x,
                                               const float* __restrict__ w,
                                               const float* __restrict__ bnp,
                                               unsigned short* __restrict__ f1hi,
                                               unsigned short* __restrict__ f1lo){
    __shared__ float ws[64*27];
    __shared__ float xr[32*28];
    __shared__ float s1[64], sh1[64];
    int tid = threadIdx.x;
    for (int i=tid;i<1728;i+=256) ws[i] = w[i];
    if (tid < 64){ s1[tid] = bnp[tid]; sh1[tid] = bnp[64+tid]; }
    int px = tid>>3, cg = tid&7;
    int p = blockIdx.x*32 + px;            // pixel
    int h = p/384, wq = p - h*384;
    for (int j=cg; j<27; j+=8){
        int ci = j/9, t9 = j - ci*9; int kh = t9/3, kw = t9 - kh*3;
        int y = h+kh-1, xx = wq+kw-1;
        float v = 0.f;
        if ((unsigned)y<384u && (unsigned)xx<384u)
            v = x[ci*147456 + y*384 + xx];
        xr[px*28+j] = v;
    }
    __syncthreads();
    float a[8];
    #pragma unroll
    for (int u=0;u<8;u++) a[u]=0.f;
    #pragma unroll
    for (int j=0;j<27;j++){
        float xv = xr[px*28+j];
        #pragma unroll
        for (int u=0;u<8;u++) a[u] += xv*ws[(cg*8+u)*27+j];
    }
    unsigned short hs[8], ls[8];
    #pragma unroll
    for (int u=0;u<8;u++){
        int co = cg*8+u;
        float v = gelu_f(a[u]*s1[co] + sh1[co]);
        split2(v, hs[u], ls[u]);
    }
    size_t off = (size_t)blockIdx.x*2048 + tid*8;   // == p*64 + cg*8
    *(float4*)(f1hi + off) = *(float4*)hs;
    *(float4*)(f1lo + off) = *(float4*)ls;
}

// ---- conv2 via split-2 bf16 MFMA (3 passes). One image.
__global__ __launch_bounds__(192) void conv2_mfma_k(
        const unsigned short* __restrict__ f1hi, const unsigned short* __restrict__ f1lo,
        const unsigned short* __restrict__ bhi,  const unsigned short* __restrict__ blo,
        const float* __restrict__ bnsc, const float* __restrict__ bnsh,
        float* __restrict__ fb){
    __shared__ __align__(16) unsigned short Ah[192*68], Al[192*68];
    __shared__ __align__(16) unsigned short Bh[64*68],  Bl[64*68];
    const int tid = threadIdx.x;
    const int bm = blockIdx.x*192;
    const int y = bm/384, x0 = bm - y*384;     // x0 in {0,192}
    const int wv = tid>>6, lane = tid&63, lm = lane&15, q = lane>>4;

    f32x4 acc[4][4];
    #pragma unroll
    for (int i=0;i<4;i++)
        #pragma unroll
        for (int j=0;j<4;j++) acc[i][j] = (f32x4){0.f,0.f,0.f,0.f};

    for (int t9=0; t9<9; t9++){
        int kh = t9/3, kw = t9 - kh*3;
        int ys = y + kh - 1;
        bool yok = ((unsigned)ys < 384u);
        #pragma unroll
        for (int i=0;i<8;i++){
            int ch = tid + i*192;
            int pr = ch>>3, c8 = (ch&7)*8;
            int xs = x0 + pr + kw - 1;
            float4 vh = {0.f,0.f,0.f,0.f}, vl = {0.f,0.f,0.f,0.f};
            if (yok && (unsigned)xs < 384u){
                size_t off = ((size_t)(ys*384 + xs))*64 + c8;
                vh = *(const float4*)(f1hi + off);
                vl = *(const float4*)(f1lo + off);
            }
            *(float4*)(Ah + pr*68 + c8) = vh;
            *(float4*)(Al + pr*68 + c8) = vl;
        }
        #pragma unroll
        for (int i=0;i<3;i++){
            int ch = tid + i*192;
            if (ch < 512){
                int n = ch>>3, c8 = (ch&7)*8;
                size_t off = (size_t)n*576 + t9*64 + c8;
                *(float4*)(Bh + n*68 + c8) = *(const float4*)(bhi + off);
                *(float4*)(Bl + n*68 + c8) = *(const float4*)(blo + off);
            }
        }
        __syncthreads();
        #pragma unroll
        for (int h=0; h<2; h++){
            bf16x8 ah[4], al[4], bh8[4], bl8[4];
            #pragma unroll
            for (int mi=0;mi<4;mi++){
                int row = wv*64 + mi*16 + lm;
                ah[mi] = *(const bf16x8*)(Ah + row*68 + h*32 + q*8);
                al[mi] = *(const bf16x8*)(Al + row*68 + h*32 + q*8);
            }
            #pragma unroll
            for (int nj=0;nj<4;nj++){
                int row = nj*16 + lm;
                bh8[nj] = *(const bf16x8*)(Bh + row*68 + h*32 + q*8);
                bl8[nj] = *(const bf16x8*)(Bl + row*68 + h*32 + q*8);
            }
            #pragma unroll
            for (int mi=0;mi<4;mi++)
                #pragma unroll
                for (int nj=0;nj<4;nj++){
                    acc[mi][nj] = __builtin_amdgcn_mfma_f32_16x16x32_bf16(ah[mi], bh8[nj], acc[mi][nj], 0,0,0);
                    acc[mi][nj] = __builtin_amdgcn_mfma_f32_16x16x32_bf16(al[mi], bh8[nj], acc[mi][nj], 0,0,0);
                    acc[mi][nj] = __builtin_amdgcn_mfma_f32_16x16x32_bf16(ah[mi], bl8[nj], acc[mi][nj], 0,0,0);
                }
        }
        __syncthreads();
    }
    #pragma unroll
    for (int nj=0;nj<4;nj++){
        int n = nj*16 + lm;
        float sc = bnsc[n], sh = bnsh[n];
        #pragma unroll
        for (int mi=0;mi<4;mi++){
            int m0 = bm + wv*64 + mi*16 + q*4;
            float4 o;
            o.x = gelu_f(acc[mi][nj][0]*sc + sh);
            o.y = gelu_f(acc[mi][nj][1]*sc + sh);
            o.z = gelu_f(acc[mi][nj][2]*sc + sh);
            o.w = gelu_f(acc[mi][nj][3]*sc + sh);
            *(float4*)(fb + (size_t)n*147456 + m0) = o;
        }
    }
}

// ---- fused variance-score + coarse patchify (one batch): block = one cell
// writes scores[cell] and Ac16[cell][c*256+py*16+px] (bf16 of fb)
__global__ __launch_bounds__(256) void varpatch_k(const float* __restrict__ fb,
                                                  float* __restrict__ scores,
                                                  unsigned short* __restrict__ Ac){
    __shared__ float buf[4096];
    __shared__ float var_s[64];
    int bid = blockIdx.x;           // 0..575
    int gy = bid/24; int gx = bid - gy*24;
    int tid = threadIdx.x;
    int cl = tid>>4, part = tid&15;
    int base = gy*16*384 + gx*16;
    unsigned short* acbase = Ac + (size_t)bid*16384;
    for (int ch=0; ch<64; ch+=16){
        #pragma unroll
        for (int i=0;i<16;i++){
            int e = tid + i*256;
            int c = e>>8; int p = e&255; int py = p>>4; int px = p&15;
            float v = fb[base + (ch+c)*147456 + py*384 + px];
            buf[e] = v;
            acbase[ch*256 + e] = f2bf(v);   // k = (ch+c)*256 + py*16 + px
        }
        __syncthreads();
        float s = 0.f;
        #pragma unroll
        for (int j=0;j<16;j++) s += buf[cl*256 + j*16 + part];
        s += __shfl_down(s,8,16); s += __shfl_down(s,4,16);
        s += __shfl_down(s,2,16); s += __shfl_down(s,1,16);
        float mean = __shfl(s,0,16) * (1.f/256.f);
        float q = 0.f;
        #pragma unroll
        for (int j=0;j<16;j++){ float d = buf[cl*256 + j*16 + part] - mean; q += d*d; }
        q += __shfl_down(q,8,16); q += __shfl_down(q,4,16);
        q += __shfl_down(q,2,16); q += __shfl_down(q,1,16);
        if (part==0) var_s[ch+cl] = q*(1.f/256.f);
        __syncthreads();
    }
    if (tid==0){
        float a=0.f;
        for (int c=0;c<64;c++) a += var_s[c];
        scores[bid] = a*(1.f/64.f);
    }
}

// ---- generic bf16 MFMA GEMM: tile M=64 x N=128, 256 thr (4 waves), K-split z
// MODE 0: coarse  A=Ac16 rows [576][16384]
// MODE 1: detail  A=Ac16 gathered: row=(topk[sel],dy,dx), k=c*64+qy*8+qx
// MODE 2: merge   A=dp16 rows [1024][3072]
template<int MODE, int KL, int MT>
__global__ __launch_bounds__(256) void gemm16_k(const unsigned short* __restrict__ A,
                                                const unsigned short* __restrict__ W,
                                                const int* __restrict__ topk,
                                                float* __restrict__ part){
    constexpr int KT = (MODE==0)?16384:(MODE==1)?4096:3072;   // W row length
    __shared__ __align__(16) unsigned short As[64*40];
    __shared__ __align__(16) unsigned short Bs[128*40];
    const int tid = threadIdx.x;
    const int nt = blockIdx.x, mt = blockIdx.y, z = blockIdx.z;
    const int m0 = mt*64, n0 = nt*128;
    const int wv = tid>>6, lane = tid&63;
    const int lm = lane&15, q = lane>>4;
    const int ar = tid>>2, ak = (tid&3)*8;

    size_t abase;
    if (MODE==1){
        int t = m0 + ar; int sel = t>>2, dd = t&3;
        int cell = topk[sel];
        abase = (size_t)cell*16384 + (dd>>1)*128 + (dd&1)*8;
    } else if (MODE==0){
        abase = (size_t)(m0+ar)*16384;
    } else {
        abase = (size_t)(m0+ar)*3072;
    }

    f32x4 acc[4][2];
    #pragma unroll
    for (int i=0;i<4;i++)
        #pragma unroll
        for (int j=0;j<2;j++)
            acc[i][j] = (f32x4){0.f,0.f,0.f,0.f};

    const int kb0 = z*KL;
    for (int kb = kb0; kb < kb0+KL; kb += 32){
        {
            int k0 = kb + ak;
            size_t src = (MODE==1) ? (abase + (k0>>6)*256 + ((k0>>3)&7)*16)
                                   : (abase + k0);
            const float4 v = *(const float4*)(A + src);
            *(float4*)(&As[ar*40 + ak]) = v;
        }
        #pragma unroll
        for (int i=0;i<2;i++){
            const float4 v = *(const float4*)(W + (size_t)(n0+ar+i*64)*KT + kb + ak);
            *(float4*)(&Bs[(ar+i*64)*40 + ak]) = v;
        }
        __syncthreads();
        bf16x8 af[4], bb[2];
        #pragma unroll
        for (int mi=0;mi<4;mi++) af[mi] = *(const bf16x8*)(&As[(mi*16+lm)*40 + q*8]);
        #pragma unroll
        for (int nj=0;nj<2;nj++) bb[nj] = *(const bf16x8*)(&Bs[(wv*32+nj*16+lm)*40 + q*8]);
        #pragma unroll
        for (int mi=0;mi<4;mi++)
            #pragma unroll
            for (int nj=0;nj<2;nj++)
                acc[mi][nj] = __builtin_amdgcn_mfma_f32_16x16x32_bf16(af[mi], bb[nj], acc[mi][nj], 0,0,0);
        __syncthreads();
    }

    float* pz = part + (size_t)z*MT*768;
    #pragma unroll
    for (int mi=0;mi<4;mi++)
        #pragma unroll
        for (int nj=0;nj<2;nj++)
            #pragma unroll
            for (int r=0;r<4;r++){
                int m = m0 + mi*16 + q*4 + r;
                int n = n0 + wv*32 + nj*16 + lm;
                pz[m*768 + n] = acc[mi][nj][r];
            }
}

// ---- sum K-split partials + bias -> f32
__global__ __launch_bounds__(256) void reduce_k(const float* __restrict__ partials,
                                                const float* __restrict__ bias,
                                                float* __restrict__ outp,
                                                int MTOT, int NSPLIT){
    int idx = blockIdx.x*256 + threadIdx.x;
    int col = idx % 768;
    float s = bias[col];
    for (int i=0;i<NSPLIT;i++) s += partials[(size_t)i*MTOT*768 + idx];
    outp[idx] = s;
}

// ---- sum K-split partials + bias -> bf16
__global__ __launch_bounds__(256) void reduce16_k(const float* __restrict__ partials,
                                                  const float* __restrict__ bias,
                                                  unsigned short* __restrict__ outp,
                                                  int MTOT, int NSPLIT){
    int idx = blockIdx.x*256 + threadIdx.x;
    int col = idx % 768;
    float s = bias[col];
    for (int i=0;i<NSPLIT;i++) s += partials[(size_t)i*MTOT*768 + idx];
    outp[idx] = f2bf(s);
}

// ---- top-64 of 576 (one batch), one wave; jax tie-break (lower idx first)
__global__ void topk_k(const float* __restrict__ scores, int* __restrict__ topk,
                       float* __restrict__ outf){
    int lane = threadIdx.x; // 64
    float v[9];
    #pragma unroll
    for (int j=0;j<9;j++) v[j] = scores[j*64 + lane];
    for (int k=0;k<64;k++){
        float best = -3.0e38f; int bidx = 1<<30;
        #pragma unroll
        for (int j=0;j<9;j++)
            if (v[j] > best){ best = v[j]; bidx = j*64 + lane; }
        #pragma unroll
        for (int off=32; off>0; off>>=1){
            float ov = __shfl_down(best, off);
            int oi   = __shfl_down(bidx, off);
            if (ov > best || (ov == best && oi < bidx)){ best = ov; bidx = oi; }
        }
        bidx = __shfl(bidx, 0);
        if (lane == 0){ topk[k] = bidx; outf[k] = (float)bidx; }
        if ((bidx & 63) == lane) v[bidx>>6] = -3.0e38f;
    }
}

extern "C" void kernel_launch(void* const* d_in, const int* in_sizes, int n_in,
                              void* d_out, int out_size, void* d_ws, size_t ws_size,
                              hipStream_t stream){
    const float* x       = (const float*)d_in[0];
    const float* conv1_w = (const float*)d_in[1];
    const float* bn1_g   = (const float*)d_in[2];
    const float* bn1_b   = (const float*)d_in[3];
    const float* bn1_m   = (const float*)d_in[4];
    const float* bn1_v   = (const float*)d_in[5];
    const float* conv2_w = (const float*)d_in[6];
    const float* bn2_g   = (const float*)d_in[7];
    const float* bn2_b   = (const float*)d_in[8];
    const float* bn2_m   = (const float*)d_in[9];
    const float* bn2_v   = (const float*)d_in[10];
    const float* coarse_w= (const float*)d_in[11];
    const float* coarse_b= (const float*)d_in[12];
    const float* detail_w= (const float*)d_in[13];
    const float* detail_b= (const float*)d_in[14];
    const float* merge_w = (const float*)d_in[15];
    const float* merge_b = (const float*)d_in[16];
    float* out = (float*)d_out;

    // ---- workspace layout (float units); ~151 MB ----
    float* wsp  = (float*)d_ws;
    unsigned short* f1hi = (unsigned short*)wsp;         // 9,437,184 bf16
    unsigned short* f1lo = f1hi + 9437184;               // 9,437,184 bf16
    float* fb   = wsp + 9437184;                         // 9,437,184 f32
    float* bnp  = fb + 9437184;                          // 256
    float* scores = bnp + 256;                           // 9,216
    int*   topk = (int*)(scores + 9216);                 // 1,024
    unsigned short* B2hi = (unsigned short*)(topk + 1024);   // 36,864 bf16
    unsigned short* B2lo = B2hi + 36864;                     // 36,864 bf16
    unsigned short* Wc16 = B2lo + 36864;                     // 12,582,912 bf16
    unsigned short* Wd16 = Wc16 + 12582912;                  // 3,145,728 bf16
    unsigned short* Wm16 = Wd16 + 3145728;                   // 2,359,296 bf16
    unsigned short* Ac16 = Wm16 + 2359296;                   // 9,437,184 bf16
    unsigned short* dp16 = Ac16 + 9437184;                   // 3,145,728 bf16
    float* part = (float*)(dp16 + 3145728);                  // 3,538,944 f32

    if (ws_size < (size_t)171000000) return;   // graceful fail if ws too small

    const int DETAIL_OFF = 16*576*768;            // 7077888
    const int IDX_OFF    = DETAIL_OFF + 16*64*768;// 7864320

    bnprep_k<<<1,64,0,stream>>>(bn1_g,bn1_b,bn1_m,bn1_v, bn2_g,bn2_b,bn2_m,bn2_v, bnp);
    w2prep_k<<<144,256,0,stream>>>(conv2_w, B2hi, B2lo);
    cvtbf16_k<<<49152,256,0,stream>>>(coarse_w, Wc16, 12582912);
    cvtbf16_k<<<12288,256,0,stream>>>(detail_w, Wd16, 3145728);
    cvtbf16_k<<<9216,256,0,stream>>>(merge_w,  Wm16, 2359296);

    for (int b = 0; b < 16; b++){
        conv1_k<<<4608,256,0,stream>>>(x + (size_t)b*442368, conv1_w, bnp, f1hi, f1lo);
        conv2_mfma_k<<<768,192,0,stream>>>(f1hi, f1lo, B2hi, B2lo, bnp+128, bnp+192, fb);
        varpatch_k<<<576,256,0,stream>>>(fb, scores + b*576, Ac16);
        topk_k<<<1,64,0,stream>>>(scores + b*576, topk + b*64, out + IDX_OFF + b*64);
        // coarse tokens
        gemm16_k<0,2048,576><<<dim3(6,9,8),256,0,stream>>>(Ac16, Wc16, nullptr, part);
        reduce_k<<<1728,256,0,stream>>>(part, coarse_b, out + (size_t)b*442368, 576, 8);
        // detail tokens (selected) — A gathered from Ac16
        gemm16_k<1,1024,256><<<dim3(6,4,4),256,0,stream>>>(Ac16, Wd16, topk + b*64, part);
        reduce16_k<<<768,256,0,stream>>>(part, detail_b, dp16 + (size_t)b*196608, 256, 4);
    }

    // merge over all batches: M=1024, K=3072
    gemm16_k<2,768,1024><<<dim3(6,16,4),256,0,stream>>>(dp16, Wm16, nullptr, part);
    reduce_k<<<3072,256,0,stream>>>(part, merge_b, out + DETAIL_OFF, 1024, 4);
}